// Round 6
// baseline (296.332 us; speedup 1.0000x reference)
//
#include <hip/hip_runtime.h>
#include <hip/hip_bf16.h>

#define NAQ 35
#define NME 18
#define NN  53
#define FD  64
#define CTXD 60
#define PERB 2          // batch elements per block

// ---- LDS layout (floats) ----
#define L_WX    0       // 2048: WXA @0, WXM @1024
#define L_CV    2048    // 224: folded heter-projection vectors, stride 28
#define L_SVC   2272    // 212: ctx-part of projections
#define L_A248  2484    // 4: a_vec[248] per quadrant (aa,am,ma,mm)
#define L_AT    2488    // 53 rows stride 68: attri (16B aligned)
#define L_FULLA 6092    // 35 rows stride 25
#define L_FULLM 6967    // 18 rows stride 27
#define L_SVW   7453    // 4*53 per-element projections
#define L_RINV  7665    // 53
#define L_PT    6092    // u16 alias: P^T 53(j) x 56(i) bf16 over FULLA/FULLM/SVW
#define S_TOTAL 7718    // 30,872 B -> 5 blocks/CU

typedef unsigned int   u32;
typedef unsigned short u16;

__device__ __forceinline__ float ldf(const void* p, long i, bool bf) {
  if (bf) { u16 h = ((const u16*)p)[i]; return __uint_as_float(((u32)h) << 16); }
  return ((const float*)p)[i];
}
__device__ __forceinline__ u16 f2bf(float f) {
  u32 u = __float_as_uint(f);
  return (u16)((u + 0x7FFFu + ((u >> 16) & 1u)) >> 16);
}
__device__ __forceinline__ bool sniff_bf16(const void* ctx) {
  const u32* w = (const u32*)ctx;
  bool ok = true;
#pragma unroll
  for (int k = 0; k < 32; ++k) {
    u32 e = (w[k] >> 7) & 0xFFu;
    ok = ok && (e >= 96u && e <= 160u);
  }
  return ok;
}
__device__ __forceinline__ float4 f4fma(float a, float4 b, float4 c) {
  c.x = fmaf(a, b.x, c.x); c.y = fmaf(a, b.y, c.y);
  c.z = fmaf(a, b.z, c.z); c.w = fmaf(a, b.w, c.w);
  return c;
}

// =======================================================================
// single fused kernel: one block = PERB batch elements
// =======================================================================
__global__ __launch_bounds__(256, 5) void hga_main(
    const void* __restrict__ aqi_inp, const void* __restrict__ meo_inp,
    const void* __restrict__ ctx, const void* __restrict__ adjn,
    const void* __restrict__ aqi_idE, const void* __restrict__ aqi_monthE,
    const void* __restrict__ aqi_weekdayE, const void* __restrict__ aqi_hourE,
    const void* __restrict__ meo_windE, const void* __restrict__ meo_idE,
    const void* __restrict__ meo_monthE, const void* __restrict__ meo_weekdayE,
    const void* __restrict__ meo_hourE,
    const void* __restrict__ Wxa, const void* __restrict__ Wxm,
    const void* __restrict__ Wua, const void* __restrict__ Wum,
    const void* __restrict__ a_aa, const void* __restrict__ a_am,
    const void* __restrict__ a_ma, const void* __restrict__ a_mm,
    const int* __restrict__ aqi_ex, const int* __restrict__ meo_ex,
    const int* __restrict__ adj, void* __restrict__ out, int B)
{
  __shared__ __align__(16) float sm[S_TOTAL];
  const int t = threadIdx.x;
  const bool bf = sniff_bf16(ctx);

  // ---- T0 (once per block): batch-invariant tables (all inputs L2-hot) ----
  for (int idx = t; idx < 2048; idx += 256) {
    float v = (idx < 1024) ? ldf(Wxa, idx, bf) : ldf(Wxm, idx - 1024, bf);
    sm[L_WX + idx] = v;
  }
  if (t < 224) {                           // CV[tr][k] = sum_f Wu[k][f]*AV_tr[f]
    int tr = t / 28, k = t - tr * 28;
    int K = (tr < 4) ? 24 : 26;
    float v = 0.f;
    if (k < K) {
      const void* Wu = (tr < 4) ? Wua : Wum;
      const void* av; int off;
      switch (tr) {
        case 0: av = a_aa; off = 0;   break;  // A-node src, aqi cols
        case 1: av = a_am; off = 0;   break;  // A-node src, meo cols
        case 2: av = a_aa; off = 124; break;  // A-node dst (aqi rows)
        case 3: av = a_ma; off = 124; break;  // A-node dst (meo rows)
        case 4: av = a_ma; off = 0;   break;  // M-node src, aqi cols
        case 5: av = a_mm; off = 0;   break;  // M-node src, meo cols
        case 6: av = a_am; off = 124; break;  // M-node dst (aqi rows)
        default: av = a_mm; off = 124; break; // M-node dst (meo rows)
      }
      float s = 0.f;
      for (int f = 0; f < 64; ++f) s += ldf(Wu, k * 64 + f, bf) * ldf(av, off + f, bf);
      v = s;
    }
    sm[L_CV + t] = v;
  }
  if (t < 212) {                           // SVC: ctx-part dots
    int arr = t / 53, i = t - arr * 53;
    int isA = (i < NAQ);
    const void* av; int off;
    if (arr == 0)      { av = isA ? a_aa : a_ma; off = 64;  }
    else if (arr == 1) { av = isA ? a_am : a_mm; off = 64;  }
    else if (arr == 2) { av = isA ? a_aa : a_am; off = 188; }
    else               { av = isA ? a_ma : a_mm; off = 188; }
    float s = 0.f;
    for (int c = 0; c < CTXD; ++c) s += ldf(ctx, i * CTXD + c, bf) * ldf(av, off + c, bf);
    sm[L_SVC + t] = s;
  }
  if (t < 4) {
    const void* av = (t == 0) ? a_aa : (t == 1) ? a_am : (t == 2) ? a_ma : a_mm;
    sm[L_A248 + t] = ldf(av, 248, bf);
  }
  __syncthreads();

  for (int e = 0; e < PERB; ++e) {
    const int b = blockIdx.x * PERB + e;
    if (b >= B) break;

    // ---- P1: feature rows (padded strides 25 / 27) ----
    for (int idx = t; idx < 840 + 468; idx += 256) {
      if (idx < 840) {
        int i = idx / 24, k = idx - i * 24;
        float v;
        if (k < 16) v = ldf(aqi_inp, ((long)b * NAQ + i) * 16 + k, bf);
        else {
          int pr = (k - 16) >> 1, d = (k - 16) & 1;
          int ee = aqi_ex[((long)b * NAQ + i) * 4 + pr];
          const void* tbl = (pr == 0) ? aqi_idE : (pr == 1) ? aqi_monthE
                           : (pr == 2) ? aqi_weekdayE : aqi_hourE;
          v = ldf(tbl, ee * 2 + d, bf);
        }
        sm[L_FULLA + i * 25 + k] = v;
      } else {
        int ix = idx - 840;
        int i = ix / 26, k = ix - i * 26;
        float v;
        if (k < 16) v = ldf(meo_inp, ((long)b * NME + i) * 16 + k, bf);
        else {
          int pr = (k - 16) >> 1, d = (k - 16) & 1;
          int ee = meo_ex[((long)b * NME + i) * 5 + pr];
          const void* tbl = (pr == 0) ? meo_windE : (pr == 1) ? meo_idE
                           : (pr == 2) ? meo_monthE : (pr == 3) ? meo_weekdayE : meo_hourE;
          v = ldf(tbl, ee * 2 + d, bf);
        }
        sm[L_FULLM + i * 27 + k] = v;
      }
    }
    __syncthreads();

    // ---- P2: attri = inp(53x16) @ Wx(16x64) -> L_AT; P3: projections ----
    {
      const int r = t >> 2, cg = t & 3;
      if (r < NN) {
        const int c0 = cg * 16;
        const float* A = (r < NAQ) ? sm + L_FULLA + r * 25
                                   : sm + L_FULLM + (r - NAQ) * 27;
        const float* W = (r < NAQ) ? sm + L_WX : sm + L_WX + 1024;
        float4 a0 = make_float4(0.f,0.f,0.f,0.f), a1 = a0, a2 = a0, a3 = a0;
#pragma unroll
        for (int k = 0; k < 16; ++k) {
          float x = A[k];
          const float4* wr = (const float4*)(W + k * 64 + c0);
          a0 = f4fma(x, wr[0], a0); a1 = f4fma(x, wr[1], a1);
          a2 = f4fma(x, wr[2], a2); a3 = f4fma(x, wr[3], a3);
        }
        float4* h = (float4*)(sm + L_AT + r * 68 + c0);
        h[0] = a0; h[1] = a1; h[2] = a2; h[3] = a3;
        // P3: svw via folded C-vectors (reads FULL only)
        const int role = cg;
        const bool isA = (r < NAQ);
        const int K = isA ? 24 : 26;
        const float* F = A;
        const float* C = sm + L_CV + ((isA ? 0 : 4) + role) * 28;
        float s = 0.f;
        for (int k = 0; k < K; ++k) s = fmaf(F[k], C[k], s);
        sm[L_SVW + role * 53 + r] = sm[L_SVC + role * 53 + r] + s;
      }
    }
    __syncthreads();

    // ---- P4: materialize P^T (bf16) once; e-values live in registers ----
    {
      const int r = t >> 2, q = t & 3;
      const bool act = (r < NN);
      const int j0 = q * 14;
      float ev[14];
      float m = -3.0e38f, ssum = 0.f;
      if (act) {
        const float s1 = sm[L_SVW + r], s2 = sm[L_SVW + 53 + r];
        const float* tb = sm + L_SVW + ((r < NAQ) ? 106 : 159);
        const int qrow = (r < NAQ) ? 0 : 2;
        const float aqL = sm[L_A248 + qrow], aqR = sm[L_A248 + qrow + 1];
#pragma unroll
        for (int jj = 0; jj < 14; ++jj) {
          const int j = j0 + jj;
          float v = -3.0e38f;
          if (j < NN) {
            int am = adj[r * NN + j];
            float an = ldf(adjn, r * NN + j, bf);
            float rr = ((j < NAQ) ? s1 : s2) + tb[j] + an * ((j < NAQ) ? aqL : aqR);
            v = (am > 0) ? ((rr > 0.f) ? rr : 0.2f * rr) : -1.0e12f;
          }
          ev[jj] = v;
          m = fmaxf(m, v);
        }
        m = fmaxf(m, __shfl_xor(m, 1, 64));
        m = fmaxf(m, __shfl_xor(m, 2, 64));
#pragma unroll
        for (int jj = 0; jj < 14; ++jj) {
          float pv = ((j0 + jj) < NN) ? __expf(ev[jj] - m) : 0.f;
          ev[jj] = pv;
          ssum += pv;
        }
        ssum += __shfl_xor(ssum, 1, 64);
        ssum += __shfl_xor(ssum, 2, 64);
      }
      __syncthreads();            // SVW/FULL reads done; PT may now clobber
      if (act) {
        u16* PT = (u16*)(sm + L_PT);
#pragma unroll
        for (int jj = 0; jj < 14; ++jj) {
          const int j = j0 + jj;
          if (j < NN) PT[j * 56 + r] = f2bf(ev[jj]);
        }
        if (q == 0) sm[L_RINV + r] = 1.f / ssum;
      }
    }
    __syncthreads();

    // ---- P5: pure GEMM2  P(53x53) @ attri(53x64) -> out ----
    {
      const int fg = t & 7, ip = t >> 3;
      if (ip < 27) {
        const int i0 = 2 * ip, i1 = i0 + 1;
        const bool two = (i1 < NN);
        const int c0 = fg * 8;
        const u16* PT = (const u16*)(sm + L_PT);
        float4 a00 = make_float4(0.f,0.f,0.f,0.f), a01 = a00, a10 = a00, a11 = a00;
        for (int j = 0; j < NN; ++j) {
          u32 w = *(const u32*)(PT + j * 56 + i0);
          float p0 = __uint_as_float(w << 16);
          float p1 = __uint_as_float(w & 0xFFFF0000u);
          const float4* ar = (const float4*)(sm + L_AT + j * 68 + c0);
          float4 w0 = ar[0], w1 = ar[1];
          a00 = f4fma(p0, w0, a00); a01 = f4fma(p0, w1, a01);
          a10 = f4fma(p1, w0, a10); a11 = f4fma(p1, w1, a11);
        }
        float rv0 = sm[L_RINV + i0];
        float rv1 = two ? sm[L_RINV + i1] : 0.f;
#pragma unroll
        for (int rr = 0; rr < 2; ++rr) {
          if (rr == 1 && !two) break;
          const int ii = rr ? i1 : i0;
          const float rv = rr ? rv1 : rv0;
          const float4 va = rr ? a10 : a00, vb = rr ? a11 : a01;
          long off = (ii < NAQ)
            ? (long)b * (NAQ * FD) + (long)ii * FD + c0
            : (long)B * (NAQ * FD) + (long)b * (NME * FD) + (long)(ii - NAQ) * FD + c0;
          float o0 = va.x * rv, o1 = va.y * rv, o2 = va.z * rv, o3 = va.w * rv;
          float o4 = vb.x * rv, o5 = vb.y * rv, o6 = vb.z * rv, o7 = vb.w * rv;
          if (bf) {
            uint4 pk;
            pk.x = ((u32)f2bf(o1) << 16) | f2bf(o0);
            pk.y = ((u32)f2bf(o3) << 16) | f2bf(o2);
            pk.z = ((u32)f2bf(o5) << 16) | f2bf(o4);
            pk.w = ((u32)f2bf(o7) << 16) | f2bf(o6);
            *(uint4*)((u16*)out + off) = pk;
          } else {
            float4* po = (float4*)((float*)out + off);
            po[0] = make_float4(o0, o1, o2, o3);
            po[1] = make_float4(o4, o5, o6, o7);
          }
        }
      }
    }
    __syncthreads();   // LDS reused by next element
  }
}

extern "C" void kernel_launch(void* const* d_in, const int* in_sizes, int n_in,
                              void* d_out, int out_size, void* d_ws, size_t ws_size,
                              hipStream_t stream)
{
  const void* aqi_inp      = d_in[0];
  const void* meo_inp      = d_in[1];
  const void* ctx          = d_in[2];
  const void* adjn         = d_in[3];
  const void* aqi_idE      = d_in[4];
  const void* aqi_monthE   = d_in[5];
  const void* aqi_weekdayE = d_in[6];
  const void* aqi_hourE    = d_in[7];
  const void* meo_windE    = d_in[8];
  const void* meo_idE      = d_in[9];
  const void* meo_monthE   = d_in[10];
  const void* meo_weekdayE = d_in[11];
  const void* meo_hourE    = d_in[12];
  const void* Wxa          = d_in[13];
  const void* Wxm          = d_in[14];
  const void* Wua          = d_in[15];
  const void* Wum          = d_in[16];
  const void* a_aa         = d_in[17];
  const void* a_am         = d_in[18];
  const void* a_ma         = d_in[19];
  const void* a_mm         = d_in[20];
  const int*  aqi_ex       = (const int*)d_in[21];
  const int*  meo_ex       = (const int*)d_in[22];
  const int*  adj          = (const int*)d_in[23];
  const int B = in_sizes[0] / (NAQ * 16);

  hipLaunchKernelGGL(hga_main, dim3((B + PERB - 1) / PERB), dim3(256), 0, stream,
                     aqi_inp, meo_inp, ctx, adjn,
                     aqi_idE, aqi_monthE, aqi_weekdayE, aqi_hourE,
                     meo_windE, meo_idE, meo_monthE, meo_weekdayE, meo_hourE,
                     Wxa, Wxm, Wua, Wum, a_aa, a_am, a_ma, a_mm,
                     aqi_ex, meo_ex, adj, d_out, B);
}

// Round 7
// 214.564 us; speedup vs baseline: 1.3811x; 1.3811x over previous
//
#include <hip/hip_runtime.h>
#include <hip/hip_bf16.h>

#define NAQ 35
#define NME 18
#define NN  53
#define FD  64
#define CTXD 60
#define PERB 2          // batch elements per block

// ---- ws layout (floats) ----
#define WXA_OFF 0       // 16*64 W_xa
#define WXM_OFF 1024    // 16*64 W_xm
#define CV_OFF  2048    // 8*28 folded heter-projection vectors
#define SVC_OFF 2272    // 4*53 ctx-part of projections
#define EB_OFF  2484    // 53*56 masked bias (1e30 sentinel)
#define WS_FLOATS 5452

// ---- LDS layout (floats); [0,2484) mirrors ws ----
#define L_WX    0       // 2048: WXA @0, WXM @1024
#define L_CV    2048    // 224, stride 28
#define L_SVC   2272    // 212
#define L_AT    2484    // 53 rows stride 68: attri (16B aligned)
#define L_FULLA 6088    // 35 rows stride 25
#define L_FULLM 6963    // 18 rows stride 27
#define L_SVW   7449    // 4*53 per-element projections
#define L_PT    6088    // u16 alias: P^T 53(j) x 56(i) bf16 over FULLA/FULLM/SVW
#define S_TOTAL 7661    // 30,644 B -> 5 blocks/CU

typedef unsigned int   u32;
typedef unsigned short u16;

__device__ __forceinline__ float ldf(const void* p, long i, bool bf) {
  if (bf) { u16 h = ((const u16*)p)[i]; return __uint_as_float(((u32)h) << 16); }
  return ((const float*)p)[i];
}
__device__ __forceinline__ u16 f2bf(float f) {
  u32 u = __float_as_uint(f);
  return (u16)((u + 0x7FFFu + ((u >> 16) & 1u)) >> 16);
}
__device__ __forceinline__ bool sniff_bf16(const void* ctx) {
  const u32* w = (const u32*)ctx;
  bool ok = true;
#pragma unroll
  for (int k = 0; k < 32; ++k) {
    u32 e = (w[k] >> 7) & 0xFFu;
    ok = ok && (e >= 96u && e <= 160u);
  }
  return ok;
}
__device__ __forceinline__ float4 f4fma(float a, float4 b, float4 c) {
  c.x = fmaf(a, b.x, c.x); c.y = fmaf(a, b.y, c.y);
  c.z = fmaf(a, b.z, c.z); c.w = fmaf(a, b.w, c.w);
  return c;
}

// =======================================================================
// prep: batch-invariant tables -> ws  (runs every call; ws re-poisoned)
// =======================================================================
__global__ void prep_kernel(
    const void* __restrict__ ctx, const void* __restrict__ adjn,
    const void* __restrict__ Wxa, const void* __restrict__ Wxm,
    const void* __restrict__ Wua, const void* __restrict__ Wum,
    const void* __restrict__ a_aa, const void* __restrict__ a_am,
    const void* __restrict__ a_ma, const void* __restrict__ a_mm,
    const int* __restrict__ adj, float* __restrict__ ws)
{
  const bool bf = sniff_bf16(ctx);
  int tid = blockIdx.x * blockDim.x + threadIdx.x;
  if (tid < 1024) {                        // W_xa 16x64
    ws[WXA_OFF + tid] = ldf(Wxa, tid, bf);
  } else if (tid < 2048) {                 // W_xm 16x64
    ws[tid] = ldf(Wxm, tid - 1024, bf);
  } else if (tid < CV_OFF + 224) {         // CV[tr][k] = sum_f Wu[k][f]*AV_tr[f]
    int idx = tid - CV_OFF;
    int tr = idx / 28, k = idx - tr * 28;
    int K = (tr < 4) ? 24 : 26;
    float v = 0.f;
    if (k < K) {
      const void* Wu = (tr < 4) ? Wua : Wum;
      const void* av; int off;
      switch (tr) {
        case 0: av = a_aa; off = 0;   break;  // A-node src, aqi cols
        case 1: av = a_am; off = 0;   break;  // A-node src, meo cols
        case 2: av = a_aa; off = 124; break;  // A-node dst (aqi rows)
        case 3: av = a_ma; off = 124; break;  // A-node dst (meo rows)
        case 4: av = a_ma; off = 0;   break;  // M-node src, aqi cols
        case 5: av = a_mm; off = 0;   break;  // M-node src, meo cols
        case 6: av = a_am; off = 124; break;  // M-node dst (aqi rows)
        default: av = a_mm; off = 124; break; // M-node dst (meo rows)
      }
      float s = 0.f;
      for (int f = 0; f < 64; ++f) s += ldf(Wu, k * 64 + f, bf) * ldf(av, off + f, bf);
      v = s;
    }
    ws[tid] = v;
  } else if (tid < EB_OFF) {               // SVC: ctx-part dots
    int idx = tid - SVC_OFF;
    int arr = idx / 53, i = idx - arr * 53;
    int isA = (i < NAQ);
    const void* av; int off;
    if (arr == 0)      { av = isA ? a_aa : a_ma; off = 64;  }
    else if (arr == 1) { av = isA ? a_am : a_mm; off = 64;  }
    else if (arr == 2) { av = isA ? a_aa : a_am; off = 188; }
    else               { av = isA ? a_ma : a_mm; off = 188; }
    float s = 0.f;
    for (int c = 0; c < CTXD; ++c) s += ldf(ctx, i * CTXD + c, bf) * ldf(av, off + c, bf);
    ws[tid] = s;
  } else if (tid < WS_FLOATS) {            // masked bias, stride 56
    int idx = tid - EB_OFF;
    int i = idx / 56, j = idx - i * 56;
    float v = 1e30f;
    if (j < NN && adj[i * NN + j] > 0) {
      const void* aq = (i < NAQ) ? ((j < NAQ) ? a_aa : a_am)
                                 : ((j < NAQ) ? a_ma : a_mm);
      v = ldf(adjn, i * NN + j, bf) * ldf(aq, 248, bf);
    }
    ws[tid] = v;
  }
}

// =======================================================================
// main: one block = PERB batch elements
// =======================================================================
__global__ __launch_bounds__(256, 5) void hga_main(
    const void* __restrict__ aqi_inp, const void* __restrict__ meo_inp,
    const void* __restrict__ ctx,
    const void* __restrict__ aqi_idE, const void* __restrict__ aqi_monthE,
    const void* __restrict__ aqi_weekdayE, const void* __restrict__ aqi_hourE,
    const void* __restrict__ meo_windE, const void* __restrict__ meo_idE,
    const void* __restrict__ meo_monthE, const void* __restrict__ meo_weekdayE,
    const void* __restrict__ meo_hourE,
    const int* __restrict__ aqi_ex, const int* __restrict__ meo_ex,
    const float* __restrict__ ws, void* __restrict__ out, int B)
{
  __shared__ __align__(16) float sm[S_TOTAL];
  const int t = threadIdx.x;
  const bool bf = sniff_bf16(ctx);

  // ---- P0 (once): stage WX, CV, SVC (2484 floats, ws-mirrored) ----
  {
    const float4* src = (const float4*)ws;
    float4* dst = (float4*)sm;
    for (int v = t; v < 2484 / 4; v += 256) dst[v] = src[v];
  }
  __syncthreads();

  for (int e = 0; e < PERB; ++e) {
    const int b = blockIdx.x * PERB + e;
    if (b >= B) break;

    // ---- P1: feature rows (padded strides 25 / 27) ----
    for (int idx = t; idx < 840 + 468; idx += 256) {
      if (idx < 840) {
        int i = idx / 24, k = idx - i * 24;
        float v;
        if (k < 16) v = ldf(aqi_inp, ((long)b * NAQ + i) * 16 + k, bf);
        else {
          int pr = (k - 16) >> 1, d = (k - 16) & 1;
          int ee = aqi_ex[((long)b * NAQ + i) * 4 + pr];
          const void* tbl = (pr == 0) ? aqi_idE : (pr == 1) ? aqi_monthE
                           : (pr == 2) ? aqi_weekdayE : aqi_hourE;
          v = ldf(tbl, ee * 2 + d, bf);
        }
        sm[L_FULLA + i * 25 + k] = v;
      } else {
        int ix = idx - 840;
        int i = ix / 26, k = ix - i * 26;
        float v;
        if (k < 16) v = ldf(meo_inp, ((long)b * NME + i) * 16 + k, bf);
        else {
          int pr = (k - 16) >> 1, d = (k - 16) & 1;
          int ee = meo_ex[((long)b * NME + i) * 5 + pr];
          const void* tbl = (pr == 0) ? meo_windE : (pr == 1) ? meo_idE
                           : (pr == 2) ? meo_monthE : (pr == 3) ? meo_weekdayE : meo_hourE;
          v = ldf(tbl, ee * 2 + d, bf);
        }
        sm[L_FULLM + i * 27 + k] = v;
      }
    }
    __syncthreads();

    // ---- P2: attri = inp(53x16) @ Wx(16x64) -> L_AT; P3: projections ----
    {
      const int r = t >> 2, cg = t & 3;
      if (r < NN) {
        const int c0 = cg * 16;
        const float* A = (r < NAQ) ? sm + L_FULLA + r * 25
                                   : sm + L_FULLM + (r - NAQ) * 27;
        const float* W = (r < NAQ) ? sm + L_WX : sm + L_WX + 1024;
        float4 a0 = make_float4(0.f,0.f,0.f,0.f), a1 = a0, a2 = a0, a3 = a0;
#pragma unroll
        for (int k = 0; k < 16; ++k) {
          float x = A[k];
          const float4* wr = (const float4*)(W + k * 64 + c0);
          a0 = f4fma(x, wr[0], a0); a1 = f4fma(x, wr[1], a1);
          a2 = f4fma(x, wr[2], a2); a3 = f4fma(x, wr[3], a3);
        }
        float4* h = (float4*)(sm + L_AT + r * 68 + c0);
        h[0] = a0; h[1] = a1; h[2] = a2; h[3] = a3;
        // P3: svw via folded C-vectors (reads FULL only)
        const int role = cg;
        const bool isA = (r < NAQ);
        const int K = isA ? 24 : 26;
        const float* C = sm + L_CV + ((isA ? 0 : 4) + role) * 28;
        float s = 0.f;
        for (int k = 0; k < K; ++k) s = fmaf(A[k], C[k], s);
        sm[L_SVW + role * 53 + r] = sm[L_SVC + role * 53 + r] + s;
      }
    }
    __syncthreads();

    // ---- P4: materialize P^T (bf16, rinv-folded); e-values in registers ----
    {
      const int r = t >> 2, q = t & 3;
      const bool act = (r < NN);
      const int j0 = q * 14;
      float ev[14];
      float m = -3.0e38f, ssum = 0.f;
      if (act) {
        const float s1 = sm[L_SVW + r], s2 = sm[L_SVW + 53 + r];
        const float* tb = sm + L_SVW + ((r < NAQ) ? 106 : 159);
        const float* ebrow = ws + EB_OFF + r * 56;   // L1/L2-hot
#pragma unroll
        for (int jj = 0; jj < 14; ++jj) {
          const int j = j0 + jj;
          float v = -3.0e38f;
          if (j < NN) {
            float eb = ebrow[j];
            float rr = ((j < NAQ) ? s1 : s2) + tb[j] + eb;
            v = (eb > 1e29f) ? -1.0e12f : ((rr > 0.f) ? rr : 0.2f * rr);
          }
          ev[jj] = v;
          m = fmaxf(m, v);
        }
        m = fmaxf(m, __shfl_xor(m, 1, 64));
        m = fmaxf(m, __shfl_xor(m, 2, 64));
#pragma unroll
        for (int jj = 0; jj < 14; ++jj) {
          float pv = ((j0 + jj) < NN) ? __expf(ev[jj] - m) : 0.f;
          ev[jj] = pv;
          ssum += pv;
        }
        ssum += __shfl_xor(ssum, 1, 64);
        ssum += __shfl_xor(ssum, 2, 64);
      }
      __syncthreads();            // SVW/FULL reads done; PT may now clobber
      if (act) {
        const float rinv = 1.f / ssum;
        u16* PT = (u16*)(sm + L_PT);
#pragma unroll
        for (int jj = 0; jj < 14; ++jj) {
          const int j = j0 + jj;
          if (j < NN) PT[j * 56 + r] = f2bf(ev[jj] * rinv);
        }
      }
    }
    __syncthreads();

    // ---- P5: pure GEMM2  Pn(53x53) @ attri(53x64) -> out ----
    {
      const int fg = t & 7, ip = t >> 3;
      if (ip < 27) {
        const int i0 = 2 * ip, i1 = i0 + 1;
        const bool two = (i1 < NN);
        const int c0 = fg * 8;
        const u16* PT = (const u16*)(sm + L_PT);
        float4 a00 = make_float4(0.f,0.f,0.f,0.f), a01 = a00, a10 = a00, a11 = a00;
        for (int j = 0; j < NN; ++j) {
          u32 w = *(const u32*)(PT + j * 56 + i0);
          float p0 = __uint_as_float(w << 16);
          float p1 = __uint_as_float(w & 0xFFFF0000u);
          const float4* ar = (const float4*)(sm + L_AT + j * 68 + c0);
          float4 w0 = ar[0], w1 = ar[1];
          a00 = f4fma(p0, w0, a00); a01 = f4fma(p0, w1, a01);
          a10 = f4fma(p1, w0, a10); a11 = f4fma(p1, w1, a11);
        }
#pragma unroll
        for (int rr = 0; rr < 2; ++rr) {
          if (rr == 1 && !two) break;
          const int ii = rr ? i1 : i0;
          const float4 va = rr ? a10 : a00, vb = rr ? a11 : a01;
          long off = (ii < NAQ)
            ? (long)b * (NAQ * FD) + (long)ii * FD + c0
            : (long)B * (NAQ * FD) + (long)b * (NME * FD) + (long)(ii - NAQ) * FD + c0;
          if (bf) {
            uint4 pk;
            pk.x = ((u32)f2bf(va.y) << 16) | f2bf(va.x);
            pk.y = ((u32)f2bf(va.w) << 16) | f2bf(va.z);
            pk.z = ((u32)f2bf(vb.y) << 16) | f2bf(vb.x);
            pk.w = ((u32)f2bf(vb.w) << 16) | f2bf(vb.z);
            *(uint4*)((u16*)out + off) = pk;
          } else {
            float4* po = (float4*)((float*)out + off);
            po[0] = va;
            po[1] = vb;
          }
        }
      }
    }
    __syncthreads();   // LDS reused by next element
  }
}

extern "C" void kernel_launch(void* const* d_in, const int* in_sizes, int n_in,
                              void* d_out, int out_size, void* d_ws, size_t ws_size,
                              hipStream_t stream)
{
  const void* aqi_inp      = d_in[0];
  const void* meo_inp      = d_in[1];
  const void* ctx          = d_in[2];
  const void* adjn         = d_in[3];
  const void* aqi_idE      = d_in[4];
  const void* aqi_monthE   = d_in[5];
  const void* aqi_weekdayE = d_in[6];
  const void* aqi_hourE    = d_in[7];
  const void* meo_windE    = d_in[8];
  const void* meo_idE      = d_in[9];
  const void* meo_monthE   = d_in[10];
  const void* meo_weekdayE = d_in[11];
  const void* meo_hourE    = d_in[12];
  const void* Wxa          = d_in[13];
  const void* Wxm          = d_in[14];
  const void* Wua          = d_in[15];
  const void* Wum          = d_in[16];
  const void* a_aa         = d_in[17];
  const void* a_am         = d_in[18];
  const void* a_ma         = d_in[19];
  const void* a_mm         = d_in[20];
  const int*  aqi_ex       = (const int*)d_in[21];
  const int*  meo_ex       = (const int*)d_in[22];
  const int*  adj          = (const int*)d_in[23];
  float* ws = (float*)d_ws;
  const int B = in_sizes[0] / (NAQ * 16);

  hipLaunchKernelGGL(prep_kernel, dim3((WS_FLOATS + 255) / 256), dim3(256), 0, stream,
                     ctx, adjn, Wxa, Wxm, Wua, Wum, a_aa, a_am, a_ma, a_mm, adj, ws);
  hipLaunchKernelGGL(hga_main, dim3((B + PERB - 1) / PERB), dim3(256), 0, stream,
                     aqi_inp, meo_inp, ctx, aqi_idE, aqi_monthE, aqi_weekdayE, aqi_hourE,
                     meo_windE, meo_idE, meo_monthE, meo_weekdayE, meo_hourE,
                     aqi_ex, meo_ex, ws, d_out, B);
}

// Round 8
// 190.095 us; speedup vs baseline: 1.5589x; 1.1287x over previous
//
#include <hip/hip_runtime.h>
#include <hip/hip_bf16.h>

#define NAQ 35
#define NME 18
#define NN  53
#define FD  64
#define CTXD 60
#define PERB 2          // batch elements per block

// ---- ws layout (floats) ----
#define WXA_OFF 0       // 16*64 W_xa
#define WXM_OFF 1024    // 16*64 W_xm
#define CV_OFF  2048    // 8*28 folded heter-projection vectors
#define SVC_OFF 2272    // 4*53 ctx-part of projections
#define EB_OFF  2484    // 53*56 masked bias (1e30 sentinel)
#define WS_FLOATS 5452

// ---- LDS layout (floats); [0,2484) mirrors ws ----
#define L_WX    0       // 2048: WXA @0, WXM @1024
#define L_CV    2048    // 224, stride 28
#define L_SVC   2272    // 212
#define L_FULLA 2484    // 35 rows stride 25   (alias region start)
#define L_FULLM 3359    // 18 rows stride 27
#define L_SVW   3845    // 4*53
// P (u16, row-major, 64 rows x stride 72) aliases [L_FULLA, L_FULLA+2304)
#define L_ATT   4788    // u16 ATt[64][72]: attri transposed bf16 (2304 f)
#define S_TOTAL 7092    // 28,368 B -> 5 blocks/CU
#define P_STR   72      // u16 row stride (144 B: 16B-aligned, 2-way banks)

typedef unsigned int   u32;
typedef unsigned short u16;
typedef short s8v __attribute__((ext_vector_type(8)));
typedef float f4v __attribute__((ext_vector_type(4)));

__device__ __forceinline__ float ldf(const void* p, long i, bool bf) {
  if (bf) { u16 h = ((const u16*)p)[i]; return __uint_as_float(((u32)h) << 16); }
  return ((const float*)p)[i];
}
__device__ __forceinline__ u16 f2bf(float f) {
  u32 u = __float_as_uint(f);
  return (u16)((u + 0x7FFFu + ((u >> 16) & 1u)) >> 16);
}
__device__ __forceinline__ bool sniff_bf16(const void* ctx) {
  const u32* w = (const u32*)ctx;
  bool ok = true;
#pragma unroll
  for (int k = 0; k < 32; ++k) {
    u32 e = (w[k] >> 7) & 0xFFu;
    ok = ok && (e >= 96u && e <= 160u);
  }
  return ok;
}
__device__ __forceinline__ float4 f4fma(float a, float4 b, float4 c) {
  c.x = fmaf(a, b.x, c.x); c.y = fmaf(a, b.y, c.y);
  c.z = fmaf(a, b.z, c.z); c.w = fmaf(a, b.w, c.w);
  return c;
}
__device__ __forceinline__ s8v ld_frag(const u16* p) {
  union { float4 f; s8v s; } u;
  u.f = *(const float4*)(const void*)p;
  return u.s;
}

// =======================================================================
// prep: batch-invariant tables -> ws  (verified round 7)
// =======================================================================
__global__ void prep_kernel(
    const void* __restrict__ ctx, const void* __restrict__ adjn,
    const void* __restrict__ Wxa, const void* __restrict__ Wxm,
    const void* __restrict__ Wua, const void* __restrict__ Wum,
    const void* __restrict__ a_aa, const void* __restrict__ a_am,
    const void* __restrict__ a_ma, const void* __restrict__ a_mm,
    const int* __restrict__ adj, float* __restrict__ ws)
{
  const bool bf = sniff_bf16(ctx);
  int tid = blockIdx.x * blockDim.x + threadIdx.x;
  if (tid < 1024) {
    ws[WXA_OFF + tid] = ldf(Wxa, tid, bf);
  } else if (tid < 2048) {
    ws[tid] = ldf(Wxm, tid - 1024, bf);
  } else if (tid < CV_OFF + 224) {
    int idx = tid - CV_OFF;
    int tr = idx / 28, k = idx - tr * 28;
    int K = (tr < 4) ? 24 : 26;
    float v = 0.f;
    if (k < K) {
      const void* Wu = (tr < 4) ? Wua : Wum;
      const void* av; int off;
      switch (tr) {
        case 0: av = a_aa; off = 0;   break;
        case 1: av = a_am; off = 0;   break;
        case 2: av = a_aa; off = 124; break;
        case 3: av = a_ma; off = 124; break;
        case 4: av = a_ma; off = 0;   break;
        case 5: av = a_mm; off = 0;   break;
        case 6: av = a_am; off = 124; break;
        default: av = a_mm; off = 124; break;
      }
      float s = 0.f;
      for (int f = 0; f < 64; ++f) s += ldf(Wu, k * 64 + f, bf) * ldf(av, off + f, bf);
      v = s;
    }
    ws[tid] = v;
  } else if (tid < EB_OFF) {
    int idx = tid - SVC_OFF;
    int arr = idx / 53, i = idx - arr * 53;
    int isA = (i < NAQ);
    const void* av; int off;
    if (arr == 0)      { av = isA ? a_aa : a_ma; off = 64;  }
    else if (arr == 1) { av = isA ? a_am : a_mm; off = 64;  }
    else if (arr == 2) { av = isA ? a_aa : a_am; off = 188; }
    else               { av = isA ? a_ma : a_mm; off = 188; }
    float s = 0.f;
    for (int c = 0; c < CTXD; ++c) s += ldf(ctx, i * CTXD + c, bf) * ldf(av, off + c, bf);
    ws[tid] = s;
  } else if (tid < WS_FLOATS) {
    int idx = tid - EB_OFF;
    int i = idx / 56, j = idx - i * 56;
    float v = 1e30f;
    if (j < NN && adj[i * NN + j] > 0) {
      const void* aq = (i < NAQ) ? ((j < NAQ) ? a_aa : a_am)
                                 : ((j < NAQ) ? a_ma : a_mm);
      v = ldf(adjn, i * NN + j, bf) * ldf(aq, 248, bf);
    }
    ws[tid] = v;
  }
}

// =======================================================================
// main: one block = PERB batch elements; GEMM2 on MFMA
// =======================================================================
__global__ __launch_bounds__(256, 5) void hga_main(
    const void* __restrict__ aqi_inp, const void* __restrict__ meo_inp,
    const void* __restrict__ ctx,
    const void* __restrict__ aqi_idE, const void* __restrict__ aqi_monthE,
    const void* __restrict__ aqi_weekdayE, const void* __restrict__ aqi_hourE,
    const void* __restrict__ meo_windE, const void* __restrict__ meo_idE,
    const void* __restrict__ meo_monthE, const void* __restrict__ meo_weekdayE,
    const void* __restrict__ meo_hourE,
    const int* __restrict__ aqi_ex, const int* __restrict__ meo_ex,
    const float* __restrict__ ws, void* __restrict__ out, int B)
{
  __shared__ __align__(16) float sm[S_TOTAL];
  const int t = threadIdx.x;
  const bool bf = sniff_bf16(ctx);

  // ---- P0 (once): stage WX, CV, SVC ----
  {
    const float4* src = (const float4*)ws;
    float4* dst = (float4*)sm;
    for (int v = t; v < 2484 / 4; v += 256) dst[v] = src[v];
  }
  __syncthreads();

  for (int e = 0; e < PERB; ++e) {
    const int b = blockIdx.x * PERB + e;
    if (b >= B) break;

    // ---- P1: feature rows (strides 25 / 27) ----
    for (int idx = t; idx < 840 + 468; idx += 256) {
      if (idx < 840) {
        int i = idx / 24, k = idx - i * 24;
        float v;
        if (k < 16) v = ldf(aqi_inp, ((long)b * NAQ + i) * 16 + k, bf);
        else {
          int pr = (k - 16) >> 1, d = (k - 16) & 1;
          int ee = aqi_ex[((long)b * NAQ + i) * 4 + pr];
          const void* tbl = (pr == 0) ? aqi_idE : (pr == 1) ? aqi_monthE
                           : (pr == 2) ? aqi_weekdayE : aqi_hourE;
          v = ldf(tbl, ee * 2 + d, bf);
        }
        sm[L_FULLA + i * 25 + k] = v;
      } else {
        int ix = idx - 840;
        int i = ix / 26, k = ix - i * 26;
        float v;
        if (k < 16) v = ldf(meo_inp, ((long)b * NME + i) * 16 + k, bf);
        else {
          int pr = (k - 16) >> 1, d = (k - 16) & 1;
          int ee = meo_ex[((long)b * NME + i) * 5 + pr];
          const void* tbl = (pr == 0) ? meo_windE : (pr == 1) ? meo_idE
                           : (pr == 2) ? meo_monthE : (pr == 3) ? meo_weekdayE : meo_hourE;
          v = ldf(tbl, ee * 2 + d, bf);
        }
        sm[L_FULLM + i * 27 + k] = v;
      }
    }
    __syncthreads();

    // ---- P2: attri -> ATt (bf16, transposed); P3: projections; pads ----
    {
      const int r = t >> 2, cg = t & 3;
      u16* ATu = (u16*)(sm + L_ATT);
      if (r < NN) {
        const int c0 = cg * 16;
        const float* A = (r < NAQ) ? sm + L_FULLA + r * 25
                                   : sm + L_FULLM + (r - NAQ) * 27;
        const float* W = (r < NAQ) ? sm + L_WX : sm + L_WX + 1024;
        float4 a0 = make_float4(0.f,0.f,0.f,0.f), a1 = a0, a2 = a0, a3 = a0;
#pragma unroll
        for (int k = 0; k < 16; ++k) {
          float x = A[k];
          const float4* wr = (const float4*)(W + k * 64 + c0);
          a0 = f4fma(x, wr[0], a0); a1 = f4fma(x, wr[1], a1);
          a2 = f4fma(x, wr[2], a2); a3 = f4fma(x, wr[3], a3);
        }
        // transposed bf16 writes: ATt[c][r]
        ATu[(c0 +  0) * P_STR + r] = f2bf(a0.x);
        ATu[(c0 +  1) * P_STR + r] = f2bf(a0.y);
        ATu[(c0 +  2) * P_STR + r] = f2bf(a0.z);
        ATu[(c0 +  3) * P_STR + r] = f2bf(a0.w);
        ATu[(c0 +  4) * P_STR + r] = f2bf(a1.x);
        ATu[(c0 +  5) * P_STR + r] = f2bf(a1.y);
        ATu[(c0 +  6) * P_STR + r] = f2bf(a1.z);
        ATu[(c0 +  7) * P_STR + r] = f2bf(a1.w);
        ATu[(c0 +  8) * P_STR + r] = f2bf(a2.x);
        ATu[(c0 +  9) * P_STR + r] = f2bf(a2.y);
        ATu[(c0 + 10) * P_STR + r] = f2bf(a2.z);
        ATu[(c0 + 11) * P_STR + r] = f2bf(a2.w);
        ATu[(c0 + 12) * P_STR + r] = f2bf(a3.x);
        ATu[(c0 + 13) * P_STR + r] = f2bf(a3.y);
        ATu[(c0 + 14) * P_STR + r] = f2bf(a3.z);
        ATu[(c0 + 15) * P_STR + r] = f2bf(a3.w);
        // P3: svw via folded C-vectors (reads FULL only)
        const int role = cg;
        const bool isA = (r < NAQ);
        const int K = isA ? 24 : 26;
        const float* C = sm + L_CV + ((isA ? 0 : 4) + role) * 28;
        float s = 0.f;
        for (int k = 0; k < K; ++k) s = fmaf(A[k], C[k], s);
        sm[L_SVW + role * 53 + r] = sm[L_SVC + role * 53 + r] + s;
      } else {
        // zero ATt k-pad rows: k in [53,64) for all 64 cols
        for (int idx = t - 212; idx < 704; idx += 44) {
          int n = idx / 11, kk = idx - n * 11;
          ATu[n * P_STR + 53 + kk] = 0;
        }
      }
    }
    __syncthreads();

    // ---- P4: softmax -> P row-major bf16 (rinv-folded), zero-padded ----
    {
      const int r = t >> 2, q = t & 3;
      const bool act = (r < NN);
      const int j0 = q * 14;
      float ev[14];
      float m = -3.0e38f, ssum = 0.f;
      if (act) {
        const float s1 = sm[L_SVW + r], s2 = sm[L_SVW + 53 + r];
        const float* tb = sm + L_SVW + ((r < NAQ) ? 106 : 159);
        const float* ebrow = ws + EB_OFF + r * 56;   // L1/L2-hot
#pragma unroll
        for (int jj = 0; jj < 14; ++jj) {
          const int j = j0 + jj;
          float v = -3.0e38f;
          if (j < NN) {
            float eb = ebrow[j];
            float rr = ((j < NAQ) ? s1 : s2) + tb[j] + eb;
            v = (eb > 1e29f) ? -1.0e12f : ((rr > 0.f) ? rr : 0.2f * rr);
          }
          ev[jj] = v;
          m = fmaxf(m, v);
        }
        m = fmaxf(m, __shfl_xor(m, 1, 64));
        m = fmaxf(m, __shfl_xor(m, 2, 64));
#pragma unroll
        for (int jj = 0; jj < 14; ++jj) {
          float pv = ((j0 + jj) < NN) ? __expf(ev[jj] - m) : 0.f;
          ev[jj] = pv;
          ssum += pv;
        }
        ssum += __shfl_xor(ssum, 1, 64);
        ssum += __shfl_xor(ssum, 2, 64);
      }
      __syncthreads();            // SVW/FULL reads done; P may clobber alias
      u16* Pu = (u16*)(sm + L_FULLA);
      if (act) {
        const float rinv = 1.f / ssum;
#pragma unroll
        for (int jj = 0; jj < 14; ++jj) {
          const int j = j0 + jj;
          Pu[r * P_STR + j] = (j < NN) ? f2bf(ev[jj] * rinv) : (u16)0;
        }
        if (q == 0) *(uint4*)(Pu + r * P_STR + 56) = make_uint4(0,0,0,0);
      } else {
        for (int idx = t - 212; idx < 99; idx += 44) {
          int row = 53 + idx / 9, o = idx - (idx / 9) * 9;
          *(uint4*)(Pu + row * P_STR + o * 8) = make_uint4(0,0,0,0);
        }
      }
    }
    __syncthreads();

    // ---- P5: MFMA GEMM2  P(64x64) @ AT(64x64) -> out (rows<53) ----
    {
      const int lane = t & 63, w = t >> 6;
      const int mm = lane & 15, q4 = lane >> 4;
      const u16* Pu  = (const u16*)(sm + L_FULLA);
      const u16* ATu = (const u16*)(sm + L_ATT);
      const u16* Ar = Pu + (16 * w + mm) * P_STR + q4 * 8;
      s8v av0 = ld_frag(Ar);
      s8v av1 = ld_frag(Ar + 32);
#pragma unroll
      for (int nt = 0; nt < 4; ++nt) {
        const u16* Br = ATu + (16 * nt + mm) * P_STR + q4 * 8;
        s8v bv0 = ld_frag(Br);
        s8v bv1 = ld_frag(Br + 32);
        f4v acc = {0.f, 0.f, 0.f, 0.f};
        acc = __builtin_amdgcn_mfma_f32_16x16x32_bf16(av0, bv0, acc, 0, 0, 0);
        acc = __builtin_amdgcn_mfma_f32_16x16x32_bf16(av1, bv1, acc, 0, 0, 0);
        const int cgl = 16 * nt + mm;
#pragma unroll
        for (int reg = 0; reg < 4; ++reg) {
          const int rg = 16 * w + q4 * 4 + reg;
          if (rg < NN) {
            long off = (rg < NAQ)
              ? (long)b * (NAQ * FD) + (long)rg * FD + cgl
              : (long)B * (NAQ * FD) + (long)b * (NME * FD) + (long)(rg - NAQ) * FD + cgl;
            if (bf) ((u16*)out)[off] = f2bf(acc[reg]);
            else    ((float*)out)[off] = acc[reg];
          }
        }
      }
    }
    __syncthreads();   // LDS reused by next element
  }
}

extern "C" void kernel_launch(void* const* d_in, const int* in_sizes, int n_in,
                              void* d_out, int out_size, void* d_ws, size_t ws_size,
                              hipStream_t stream)
{
  const void* aqi_inp      = d_in[0];
  const void* meo_inp      = d_in[1];
  const void* ctx          = d_in[2];
  const void* adjn         = d_in[3];
  const void* aqi_idE      = d_in[4];
  const void* aqi_monthE   = d_in[5];
  const void* aqi_weekdayE = d_in[6];
  const void* aqi_hourE    = d_in[7];
  const void* meo_windE    = d_in[8];
  const void* meo_idE      = d_in[9];
  const void* meo_monthE   = d_in[10];
  const void* meo_weekdayE = d_in[11];
  const void* meo_hourE    = d_in[12];
  const void* Wxa          = d_in[13];
  const void* Wxm          = d_in[14];
  const void* Wua          = d_in[15];
  const void* Wum          = d_in[16];
  const void* a_aa         = d_in[17];
  const void* a_am         = d_in[18];
  const void* a_ma         = d_in[19];
  const void* a_mm         = d_in[20];
  const int*  aqi_ex       = (const int*)d_in[21];
  const int*  meo_ex       = (const int*)d_in[22];
  const int*  adj          = (const int*)d_in[23];
  float* ws = (float*)d_ws;
  const int B = in_sizes[0] / (NAQ * 16);

  hipLaunchKernelGGL(prep_kernel, dim3((WS_FLOATS + 255) / 256), dim3(256), 0, stream,
                     ctx, adjn, Wxa, Wxm, Wua, Wum, a_aa, a_am, a_ma, a_mm, adj, ws);
  hipLaunchKernelGGL(hga_main, dim3((B + PERB - 1) / PERB), dim3(256), 0, stream,
                     aqi_inp, meo_inp, ctx, aqi_idE, aqi_monthE, aqi_weekdayE, aqi_hourE,
                     meo_windE, meo_idE, meo_monthE, meo_weekdayE, meo_hourE,
                     aqi_ex, meo_ex, ws, d_out, B);
}

// Round 9
// 178.871 us; speedup vs baseline: 1.6567x; 1.0627x over previous
//
#include <hip/hip_runtime.h>
#include <hip/hip_bf16.h>

#define NAQ 35
#define NME 18
#define NN  53
#define FD  64
#define CTXD 60
#define PERB 2          // batch elements per block

// ---- ws layout ----
// u16 [0, 2048): Wt[64][32] bf16  (Wt[n][k] = k<16 ? Wxa[k][n] : Wxm[k-16][n])
#define CVI_F   1024    // float: 8*16 inp-part of folded C-vectors
#define CVE_F   1152    // float: 8*12 emb-part
#define SVC_F   1248    // float: 4*53 ctx-part of projections
#define EBW_F   1460    // float: 53*56 masked bias (1e30 sentinel)
#define WS_FLOATS 4428

// ---- LDS layout (float offsets; u16 regions 16B-aligned) ----
#define L_CVI   0       // 128
#define L_CVE   128     // 96
#define L_SVC   224     // 212
#define L_AF    436     // u16[64][40]: block-diag A bf16 (1280 f)
#define L_EFA   1716    // 35*9 fp32 emb (aqi)
#define L_EFM   2031    // 18*11 fp32 emb (meo)
#define L_SVW   2229    // 212
#define L_PT    2444    // u16[64][72]: P row-major bf16 (2304 f)
#define L_ATT   4748    // u16[64][72]: attri transposed bf16 (2304 f)
#define S_TOTAL 7052    // 28,208 B -> 5 blocks/CU
#define P_STR   72
#define AF_STR  40

typedef unsigned int   u32;
typedef unsigned short u16;
typedef short s8v __attribute__((ext_vector_type(8)));
typedef float f4v __attribute__((ext_vector_type(4)));

__device__ __forceinline__ float ldf(const void* p, long i, bool bf) {
  if (bf) { u16 h = ((const u16*)p)[i]; return __uint_as_float(((u32)h) << 16); }
  return ((const float*)p)[i];
}
__device__ __forceinline__ u16 f2bf(float f) {
  u32 u = __float_as_uint(f);
  return (u16)((u + 0x7FFFu + ((u >> 16) & 1u)) >> 16);
}
__device__ __forceinline__ bool sniff_bf16(const void* ctx) {
  const u32* w = (const u32*)ctx;
  bool ok = true;
#pragma unroll
  for (int k = 0; k < 32; ++k) {
    u32 e = (w[k] >> 7) & 0xFFu;
    ok = ok && (e >= 96u && e <= 160u);
  }
  return ok;
}
__device__ __forceinline__ s8v ld_frag(const u16* p) {
  union { float4 f; s8v s; } u;
  u.f = *(const float4*)(const void*)p;
  return u.s;
}

// =======================================================================
// prep: batch-invariant tables -> ws
// =======================================================================
__global__ void prep_kernel(
    const void* __restrict__ ctx, const void* __restrict__ adjn,
    const void* __restrict__ Wxa, const void* __restrict__ Wxm,
    const void* __restrict__ Wua, const void* __restrict__ Wum,
    const void* __restrict__ a_aa, const void* __restrict__ a_am,
    const void* __restrict__ a_ma, const void* __restrict__ a_mm,
    const int* __restrict__ adj, float* __restrict__ ws)
{
  const bool bf = sniff_bf16(ctx);
  int tid = blockIdx.x * blockDim.x + threadIdx.x;
  if (tid < 2048) {                        // Wt[n][k] bf16
    int n = tid >> 5, kk = tid & 31;
    float v = (kk < 16) ? ldf(Wxa, kk * 64 + n, bf)
                        : ldf(Wxm, (kk - 16) * 64 + n, bf);
    ((u16*)ws)[tid] = f2bf(v);
    return;
  }
  int fi = tid - 1024;                     // float index (tid-2048+1024)
  if (fi < CVE_F) {                        // CVi[tr][k], k<16 (inp dims)
    int idx = fi - CVI_F;
    int tr = idx >> 4, k = idx & 15;
    const void* Wu = (tr < 4) ? Wua : Wum;
    const void* av; int off;
    switch (tr) {
      case 0: av = a_aa; off = 0;   break;
      case 1: av = a_am; off = 0;   break;
      case 2: av = a_aa; off = 124; break;
      case 3: av = a_ma; off = 124; break;
      case 4: av = a_ma; off = 0;   break;
      case 5: av = a_mm; off = 0;   break;
      case 6: av = a_am; off = 124; break;
      default: av = a_mm; off = 124; break;
    }
    float s = 0.f;
    for (int f = 0; f < 64; ++f) s += ldf(Wu, k * 64 + f, bf) * ldf(av, off + f, bf);
    ws[fi] = s;
  } else if (fi < SVC_F) {                 // CVe[tr][e] (emb dims)
    int idx = fi - CVE_F;
    int tr = idx / 12, e = idx - tr * 12;
    int E = (tr < 4) ? 8 : 10;
    float v = 0.f;
    if (e < E) {
      const void* Wu = (tr < 4) ? Wua : Wum;
      const void* av; int off;
      switch (tr) {
        case 0: av = a_aa; off = 0;   break;
        case 1: av = a_am; off = 0;   break;
        case 2: av = a_aa; off = 124; break;
        case 3: av = a_ma; off = 124; break;
        case 4: av = a_ma; off = 0;   break;
        case 5: av = a_mm; off = 0;   break;
        case 6: av = a_am; off = 124; break;
        default: av = a_mm; off = 124; break;
      }
      float s = 0.f;
      for (int f = 0; f < 64; ++f) s += ldf(Wu, (16 + e) * 64 + f, bf) * ldf(av, off + f, bf);
      v = s;
    }
    ws[fi] = v;
  } else if (fi < EBW_F) {                 // SVC: ctx-part dots
    int idx = fi - SVC_F;
    int arr = idx / 53, i = idx - arr * 53;
    int isA = (i < NAQ);
    const void* av; int off;
    if (arr == 0)      { av = isA ? a_aa : a_ma; off = 64;  }
    else if (arr == 1) { av = isA ? a_am : a_mm; off = 64;  }
    else if (arr == 2) { av = isA ? a_aa : a_am; off = 188; }
    else               { av = isA ? a_ma : a_mm; off = 188; }
    float s = 0.f;
    for (int c = 0; c < CTXD; ++c) s += ldf(ctx, i * CTXD + c, bf) * ldf(av, off + c, bf);
    ws[fi] = s;
  } else if (fi < WS_FLOATS) {             // EB masked bias, stride 56
    int idx = fi - EBW_F;
    int i = idx / 56, j = idx - i * 56;
    float v = 1e30f;
    if (j < NN && adj[i * NN + j] > 0) {
      const void* aq = (i < NAQ) ? ((j < NAQ) ? a_aa : a_am)
                                 : ((j < NAQ) ? a_ma : a_mm);
      v = ldf(adjn, i * NN + j, bf) * ldf(aq, 248, bf);
    }
    ws[fi] = v;
  }
}

// =======================================================================
// main: one block = PERB batch elements; GEMM1 and GEMM2 on MFMA
// =======================================================================
__global__ __launch_bounds__(256, 5) void hga_main(
    const void* __restrict__ aqi_inp, const void* __restrict__ meo_inp,
    const void* __restrict__ ctx,
    const void* __restrict__ aqi_idE, const void* __restrict__ aqi_monthE,
    const void* __restrict__ aqi_weekdayE, const void* __restrict__ aqi_hourE,
    const void* __restrict__ meo_windE, const void* __restrict__ meo_idE,
    const void* __restrict__ meo_monthE, const void* __restrict__ meo_weekdayE,
    const void* __restrict__ meo_hourE,
    const int* __restrict__ aqi_ex, const int* __restrict__ meo_ex,
    const float* __restrict__ ws, void* __restrict__ out, int B)
{
  __shared__ __align__(16) float sm[S_TOTAL];
  const int t = threadIdx.x;
  const bool bf = sniff_bf16(ctx);
  u16* AFu = (u16*)(sm + L_AF);
  u16* ATu = (u16*)(sm + L_ATT);
  u16* Pu  = (u16*)(sm + L_PT);

  // ---- P0 (once): stage CVI/CVE/SVC (436 floats) ----
  {
    const float4* src = (const float4*)(ws + CVI_F);
    float4* dst = (float4*)sm;
    for (int v = t; v < 109; v += 256) dst[v] = src[v];
  }
  __syncthreads();

  for (int e = 0; e < PERB; ++e) {
    const int b = blockIdx.x * PERB + e;
    if (b >= B) break;

    // ---- P1: build Af (block-diag bf16), Ef, zero-fills, ATt pad rows ----
    for (int idx = t; idx < 654; idx += 256) {
      if (idx < 140) {                     // aqi inp -> Af[r][0..15]
        int r = idx >> 2, j = idx & 3;
        uint2 v;
        if (bf) v = ((const uint2*)aqi_inp)[((long)b * NAQ + r) * 4 + j];
        else {
          float4 f = ((const float4*)aqi_inp)[((long)b * NAQ + r) * 4 + j];
          v.x = ((u32)f2bf(f.y) << 16) | f2bf(f.x);
          v.y = ((u32)f2bf(f.w) << 16) | f2bf(f.z);
        }
        *(uint2*)(AFu + r * AF_STR + j * 4) = v;
      } else if (idx < 212) {              // meo inp -> Af[35+i][16..31]
        int z = idx - 140;
        int i = z >> 2, j = z & 3;
        uint2 v;
        if (bf) v = ((const uint2*)meo_inp)[((long)b * NME + i) * 4 + j];
        else {
          float4 f = ((const float4*)meo_inp)[((long)b * NME + i) * 4 + j];
          v.x = ((u32)f2bf(f.y) << 16) | f2bf(f.x);
          v.y = ((u32)f2bf(f.w) << 16) | f2bf(f.z);
        }
        *(uint2*)(AFu + (NAQ + i) * AF_STR + 16 + j * 4) = v;
      } else if (idx < 352) {              // zero Af[r][16..31] (aqi)
        int z = idx - 212;
        int r = z >> 2, j = z & 3;
        *(uint2*)(AFu + r * AF_STR + 16 + j * 4) = make_uint2(0, 0);
      } else if (idx < 424) {              // zero Af[35+i][0..15] (meo)
        int z = idx - 352;
        int i = z >> 2, j = z & 3;
        *(uint2*)(AFu + (NAQ + i) * AF_STR + j * 4) = make_uint2(0, 0);
      } else if (idx < 564) {              // aqi embeddings -> EfA
        int z = idx - 424;
        int r = z >> 2, p = z & 3;
        int ee = aqi_ex[((long)b * NAQ + r) * 4 + p];
        const void* tbl = (p == 0) ? aqi_idE : (p == 1) ? aqi_monthE
                         : (p == 2) ? aqi_weekdayE : aqi_hourE;
        sm[L_EFA + r * 9 + p * 2]     = ldf(tbl, ee * 2, bf);
        sm[L_EFA + r * 9 + p * 2 + 1] = ldf(tbl, ee * 2 + 1, bf);
      } else {                             // meo embeddings -> EfM
        int z = idx - 564;
        int i = z / 5, p = z - i * 5;
        int ee = meo_ex[((long)b * NME + i) * 5 + p];
        const void* tbl = (p == 0) ? meo_windE : (p == 1) ? meo_idE
                         : (p == 2) ? meo_monthE : (p == 3) ? meo_weekdayE : meo_hourE;
        sm[L_EFM + i * 11 + p * 2]     = ldf(tbl, ee * 2, bf);
        sm[L_EFM + i * 11 + p * 2 + 1] = ldf(tbl, ee * 2 + 1, bf);
      }
    }
    {   // zero ATt pad rows k=53..63 (so P5's B-frag k-pads are 0-safe)
      int c = t & 63;
      for (int kk = t >> 6; kk < 11; kk += 4) ATu[c * P_STR + 53 + kk] = 0;
    }
    __syncthreads();

    // ---- P2: MFMA GEMM1  Af(64x32) @ Wt^T(32x64) -> ATt ; P3: projections ----
    {
      const int lane = t & 63, w = t >> 6;
      const int mm = lane & 15, q4 = lane >> 4;
      s8v av = ld_frag(AFu + (16 * w + mm) * AF_STR + q4 * 8);
      const u16* wt = (const u16*)ws;       // Wt bf16, L1-hot
      s8v bv0 = ld_frag(wt + (mm)      * 32 + q4 * 8);
      s8v bv1 = ld_frag(wt + (16 + mm) * 32 + q4 * 8);
      s8v bv2 = ld_frag(wt + (32 + mm) * 32 + q4 * 8);
      s8v bv3 = ld_frag(wt + (48 + mm) * 32 + q4 * 8);
#pragma unroll
      for (int nt = 0; nt < 4; ++nt) {
        f4v acc = {0.f, 0.f, 0.f, 0.f};
        s8v bv = (nt == 0) ? bv0 : (nt == 1) ? bv1 : (nt == 2) ? bv2 : bv3;
        acc = __builtin_amdgcn_mfma_f32_16x16x32_bf16(av, bv, acc, 0, 0, 0);
        const int c = nt * 16 + mm;
#pragma unroll
        for (int reg = 0; reg < 4; ++reg) {
          const int r = 16 * w + q4 * 4 + reg;
          if (r < NN) ATu[c * P_STR + r] = f2bf(acc[reg]);
        }
      }
      // P3: svw = SVC + dot(inp, CVi) + dot(emb, CVe)
      if (t < 212) {
        const int r = t >> 2, role = t & 3;
        const bool isA = (r < NAQ);
        const int tr = (isA ? 0 : 4) + role;
        const u16* arow = AFu + r * AF_STR + (isA ? 0 : 16);
        const float* Ci = sm + L_CVI + tr * 16;
        float s = 0.f;
#pragma unroll
        for (int k = 0; k < 16; ++k)
          s = fmaf(__uint_as_float(((u32)arow[k]) << 16), Ci[k], s);
        const int E = isA ? 8 : 10;
        const float* Ef = isA ? (sm + L_EFA + r * 9) : (sm + L_EFM + (r - NAQ) * 11);
        const float* Ce = sm + L_CVE + tr * 12;
        for (int k = 0; k < E; ++k) s = fmaf(Ef[k], Ce[k], s);
        sm[L_SVW + role * 53 + r] = sm[L_SVC + role * 53 + r] + s;
      }
    }
    __syncthreads();

    // ---- P4: softmax -> P row-major bf16 (rinv-folded), zero-padded ----
    {
      const int r = t >> 2, q = t & 3;
      const int j0 = q * 14;
      if (r < NN) {
        float ev[14];
        float m = -3.0e38f, ssum = 0.f;
        const float s1 = sm[L_SVW + r], s2 = sm[L_SVW + 53 + r];
        const float* tb = sm + L_SVW + ((r < NAQ) ? 106 : 159);
        const float* ebrow = ws + EBW_F + r * 56;   // L1/L2-hot
#pragma unroll
        for (int jj = 0; jj < 14; ++jj) {
          const int j = j0 + jj;
          float v = -3.0e38f;
          if (j < NN) {
            float eb = ebrow[j];
            float rr = ((j < NAQ) ? s1 : s2) + tb[j] + eb;
            v = (eb > 1e29f) ? -1.0e12f : ((rr > 0.f) ? rr : 0.2f * rr);
          }
          ev[jj] = v;
          m = fmaxf(m, v);
        }
        m = fmaxf(m, __shfl_xor(m, 1, 64));
        m = fmaxf(m, __shfl_xor(m, 2, 64));
#pragma unroll
        for (int jj = 0; jj < 14; ++jj) {
          float pv = ((j0 + jj) < NN) ? __expf(ev[jj] - m) : 0.f;
          ev[jj] = pv;
          ssum += pv;
        }
        ssum += __shfl_xor(ssum, 1, 64);
        ssum += __shfl_xor(ssum, 2, 64);
        const float rinv = 1.f / ssum;
#pragma unroll
        for (int jj = 0; jj < 14; ++jj) {
          const int j = j0 + jj;
          Pu[r * P_STR + j] = (j < NN) ? f2bf(ev[jj] * rinv) : (u16)0;
        }
        if (q == 0) *(uint4*)(Pu + r * P_STR + 56) = make_uint4(0, 0, 0, 0);
      } else {
        // zero P pad rows 53..63
        for (int idx = t - 212; idx < 99; idx += 44) {
          int row = 53 + idx / 9, o = idx - (idx / 9) * 9;
          *(uint4*)(Pu + row * P_STR + o * 8) = make_uint4(0, 0, 0, 0);
        }
      }
    }
    __syncthreads();

    // ---- P5: MFMA GEMM2  P(64x64) @ AT(64x64) -> out (rows<53) ----
    {
      const int lane = t & 63, w = t >> 6;
      const int mm = lane & 15, q4 = lane >> 4;
      const u16* Ar = Pu + (16 * w + mm) * P_STR + q4 * 8;
      s8v av0 = ld_frag(Ar);
      s8v av1 = ld_frag(Ar + 32);
#pragma unroll
      for (int nt = 0; nt < 4; ++nt) {
        const u16* Br = ATu + (16 * nt + mm) * P_STR + q4 * 8;
        s8v bv0 = ld_frag(Br);
        s8v bv1 = ld_frag(Br + 32);
        f4v acc = {0.f, 0.f, 0.f, 0.f};
        acc = __builtin_amdgcn_mfma_f32_16x16x32_bf16(av0, bv0, acc, 0, 0, 0);
        acc = __builtin_amdgcn_mfma_f32_16x16x32_bf16(av1, bv1, acc, 0, 0, 0);
        const int cgl = 16 * nt + mm;
#pragma unroll
        for (int reg = 0; reg < 4; ++reg) {
          const int rg = 16 * w + q4 * 4 + reg;
          if (rg < NN) {
            long off = (rg < NAQ)
              ? (long)b * (NAQ * FD) + (long)rg * FD + cgl
              : (long)B * (NAQ * FD) + (long)b * (NME * FD) + (long)(rg - NAQ) * FD + cgl;
            if (bf) ((u16*)out)[off] = f2bf(acc[reg]);
            else    ((float*)out)[off] = acc[reg];
          }
        }
      }
    }
    __syncthreads();   // LDS reused by next element
  }
}

extern "C" void kernel_launch(void* const* d_in, const int* in_sizes, int n_in,
                              void* d_out, int out_size, void* d_ws, size_t ws_size,
                              hipStream_t stream)
{
  const void* aqi_inp      = d_in[0];
  const void* meo_inp      = d_in[1];
  const void* ctx          = d_in[2];
  const void* adjn         = d_in[3];
  const void* aqi_idE      = d_in[4];
  const void* aqi_monthE   = d_in[5];
  const void* aqi_weekdayE = d_in[6];
  const void* aqi_hourE    = d_in[7];
  const void* meo_windE    = d_in[8];
  const void* meo_idE      = d_in[9];
  const void* meo_monthE   = d_in[10];
  const void* meo_weekdayE = d_in[11];
  const void* meo_hourE    = d_in[12];
  const void* Wxa          = d_in[13];
  const void* Wxm          = d_in[14];
  const void* Wua          = d_in[15];
  const void* Wum          = d_in[16];
  const void* a_aa         = d_in[17];
  const void* a_am         = d_in[18];
  const void* a_ma         = d_in[19];
  const void* a_mm         = d_in[20];
  const int*  aqi_ex       = (const int*)d_in[21];
  const int*  meo_ex       = (const int*)d_in[22];
  const int*  adj          = (const int*)d_in[23];
  float* ws = (float*)d_ws;
  const int B = in_sizes[0] / (NAQ * 16);

  hipLaunchKernelGGL(prep_kernel, dim3((5452 + 255) / 256), dim3(256), 0, stream,
                     ctx, adjn, Wxa, Wxm, Wua, Wum, a_aa, a_am, a_ma, a_mm, adj, ws);
  hipLaunchKernelGGL(hga_main, dim3((B + PERB - 1) / PERB), dim3(256), 0, stream,
                     aqi_inp, meo_inp, ctx, aqi_idE, aqi_monthE, aqi_weekdayE, aqi_hourE,
                     meo_windE, meo_idE, meo_monthE, meo_weekdayE, meo_hourE,
                     aqi_ex, meo_ex, ws, d_out, B);
}